// Round 10
// baseline (763.171 us; speedup 1.0000x reference)
//
#include <hip/hip_runtime.h>

// Problem constants (match reference setup_inputs)
constexpr int L = 64;
constexpr int P = 32768;
constexpr int N = L * P;          // 2,097,152 nodes
constexpr int E_PER = 262144;     // edges per non-source level
constexpr int NLEVELS = L - 1;    // 63 edge sets

constexpr int BLOCK = 1024;                 // 16 waves/block, 1 block/CU
constexpr int GRID  = 256;                  // cooperative grid
constexpr int GROUPS = 16;
constexpr int GROUP_SIZE = GRID / GROUPS;
constexpr int SLOT = 32;                    // u32 per barrier slot (128 B)

constexpr int SLICE   = 128;                // nodes per slice = P/256
constexpr int NCHUNK  = 8;                  // edge chunks per level
constexpr int CHUNK_E = E_PER / NCHUNK;     // 32768
constexpr int CAP     = 256;                // entries per (bucket,chunk) cell
                                            // mean 128; P(overflow)~3e-22/cell

// ws layout (bytes):
//   [0, 4096)        barrier counters + overflow flag (u32[1024], zeroed/launch)
//   [4096, ...)      CNT[63][256][8]  per-cell entry counts
//   [1 MiB, ...)     SRT cells: [63][256][8][CAP] packed edges
constexpr int    FLAG_IDX = 768;            // u32 index of overflow flag
constexpr size_t WS_CNT   = 4096;
constexpr size_t WS_SRT   = (size_t)1 << 20;
constexpr size_t WS_NEED  = WS_SRT + (size_t)NLEVELS * 256 * NCHUNK * CAP * 4;

typedef float vfloat4 __attribute__((ext_vector_type(4)));

// ---------------- split-phase grid barrier (proven R3-R9) ------------------
__device__ __forceinline__ void bar_arrive(unsigned bar, unsigned* gcnt,
                                           unsigned* grel, unsigned* grpcnt) {
    const unsigned old = __hip_atomic_fetch_add(
        grpcnt, 1u, __ATOMIC_RELAXED, __HIP_MEMORY_SCOPE_AGENT);
    if (old == bar * GROUP_SIZE - 1) {
        const unsigned o2 = __hip_atomic_fetch_add(
            gcnt, 1u, __ATOMIC_RELAXED, __HIP_MEMORY_SCOPE_AGENT);
        if (o2 == bar * GROUPS - 1)
            __hip_atomic_store(grel, bar, __ATOMIC_RELAXED,
                               __HIP_MEMORY_SCOPE_AGENT);
    }
}
__device__ __forceinline__ void bar_wait(unsigned bar, unsigned* grel) {
    while (__hip_atomic_load(grel, __ATOMIC_RELAXED,
                             __HIP_MEMORY_SCOPE_AGENT) < bar)
        __builtin_amdgcn_s_sleep(1);
}

__global__ void __launch_bounds__(1024)
ws_init(unsigned* __restrict__ ws) { ws[threadIdx.x] = 0u; }

// ---------- single-pass fixed-capacity scatter (replaces hist+scan+scatter)
// One block per (level, chunk). Packed word: si | (loc&127)<<21 (si < 2^21).
// Plain stores (L2 allocate -> line coalescing); counts written at the end.
__global__ void __launch_bounds__(1024)
k_scatter(const int* __restrict__ src, const int* __restrict__ dst,
          unsigned* __restrict__ ws) {
    const int l = blockIdx.x >> 3;
    const int c = blockIdx.x & 7;
    __shared__ unsigned cur[256];
    if (threadIdx.x < 256) cur[threadIdx.x] = 0u;
    __syncthreads();
    unsigned* SRT = (unsigned*)((char*)ws + WS_SRT);
    const int base = l * E_PER + c * CHUNK_E;
    bool ovf = false;
    for (int i = threadIdx.x; i < CHUNK_E; i += 1024) {
        const unsigned si  = (unsigned)src[base + i];
        const int      loc = dst[base + i] - (l + 1) * P;    // 0..P-1
        const int      bkt = loc >> 7;                        // owner block
        const unsigned pos = atomicAdd(&cur[bkt], 1u);        // LDS cursor
        if (pos < (unsigned)CAP)
            SRT[(size_t)(((l * 256 + bkt) * NCHUNK + c)) * CAP + pos]
                = si | ((unsigned)(loc & 127) << 21);
        else
            ovf = true;                                       // ~impossible
    }
    if (ovf)
        __hip_atomic_store(ws + FLAG_IDX, 1u, __ATOMIC_RELAXED,
                           __HIP_MEMORY_SCOPE_AGENT);
    __syncthreads();
    if (threadIdx.x < 256) {
        unsigned n = cur[threadIdx.x];
        if (n > (unsigned)CAP) n = CAP;
        ((unsigned*)((char*)ws + WS_CNT))
            [(size_t)(l * 256 + threadIdx.x) * NCHUNK + c] = n;
    }
}

// ---------------- main persistent kernel (R9-proven structure) -------------
// Sorted path: block b owns slice b of every level; LDS atomicMax accumulate;
// 128 coalesced sc1 finals per level. Fallback path (overflow flag / small
// ws): the R7-proven edge-parallel loop, always correct.
__global__ void __launch_bounds__(BLOCK, 1)
pathfinder_main(const float* __restrict__ hdr, const int* __restrict__ src,
                const int* __restrict__ dst, float* __restrict__ out,
                unsigned* __restrict__ ws) {
    const int b = blockIdx.x, tid = threadIdx.x, g = b >> 4;
    unsigned* const gcnt   = ws;
    unsigned* const grel   = ws + SLOT;
    unsigned* const grpcnt = ws + (2 + g) * SLOT;
    unsigned* const outu   = (unsigned*)out;

    if (ws[FLAG_IDX] != 0u) {
        // ---- fallback: R7-proven path (unsorted, global atomics) ----
        const int t = b * BLOCK + tid;
        {
            const vfloat4* hdr4 = (const vfloat4*)hdr;
            const vfloat4 a = hdr4[t];
            const vfloat4 c = hdr4[t + E_PER];
            #pragma unroll
            for (int j = 0; j < 4; ++j) {
                __hip_atomic_store(outu + 4 * t + j, __float_as_uint(a[j]),
                                   __ATOMIC_RELAXED, __HIP_MEMORY_SCOPE_AGENT);
                __hip_atomic_store(outu + 4 * (t + E_PER) + j,
                                   __float_as_uint(c[j]),
                                   __ATOMIC_RELAXED, __HIP_MEMORY_SCOPE_AGENT);
            }
        }
        int si0 = src[t], di0 = dst[t];
        int si1 = src[E_PER + t], di1 = dst[E_PER + t];
        __syncthreads();
        if (tid == 0) { bar_arrive(1u, gcnt, grel, grpcnt); bar_wait(1u, grel); }
        __syncthreads();
        for (int l = 0; l < NLEVELS; ++l) {
            if (si0 >= l * P)
                atomicMax(outu + di0, __float_as_uint(out[si0] + 1.0f));
            if (l == NLEVELS - 1) break;
            __syncthreads();
            if (tid == 0) bar_arrive((unsigned)(l + 2), gcnt, grel, grpcnt);
            int si2 = 0, di2 = 0;
            if (l + 2 < NLEVELS) {
                const size_t base = (size_t)(l + 2) * E_PER;
                si2 = src[base + t]; di2 = dst[base + t];
            }
            if (si1 < (l + 1) * P)
                atomicMax(outu + di1, __float_as_uint(out[si1] + 1.0f));
            if (tid == 0) bar_wait((unsigned)(l + 2), grel);
            __syncthreads();
            si0 = si1; di0 = di1; si1 = si2; di1 = di2;
        }
        return;
    }

    // ---- sorted path ----
    const unsigned* CNT = (const unsigned*)((char*)ws + WS_CNT);
    const unsigned* SRT = (const unsigned*)((char*)ws + WS_SRT);

    __shared__ unsigned vals[2][SLICE];
    if (tid < SLICE) { vals[0][tid] = 0u; vals[1][tid] = 0u; }
    if (tid < SLICE)
        __hip_atomic_store(outu + b * SLICE + tid,
                           __float_as_uint(hdr[b * SLICE + tid]),
                           __ATOMIC_RELAXED, __HIP_MEMORY_SCOPE_AGENT);
    __syncthreads();

    // set 0: all sources in level 0 (hdr) -> fully processable pre-barrier
    {
        const unsigned* cr = CNT + (size_t)b * NCHUNK;
        unsigned cnt[8]; unsigned tot = 0;
        #pragma unroll
        for (int c = 0; c < 8; ++c) { cnt[c] = cr[c]; tot += cnt[c]; }
        const size_t cb = (size_t)(b * NCHUNK) * CAP;
        for (unsigned e = tid; e < tot; e += BLOCK) {
            unsigned off = e; int c = 0;
            while (off >= cnt[c]) { off -= cnt[c]; ++c; }
            const unsigned w  = SRT[cb + (size_t)c * CAP + off];
            const unsigned si = w & 0x1FFFFFu;
            atomicMax(&vals[0][w >> 21], __float_as_uint(hdr[si] + 1.0f));
        }
    }
    __syncthreads();
    if (tid < SLICE) {                       // finals level 1 + rezero
        const int node = P + b * SLICE + tid;
        unsigned m = vals[0][tid];
        const unsigned hb = __float_as_uint(hdr[node]);
        if (hb > m) m = hb;
        __hip_atomic_store(outu + node, m, __ATOMIC_RELAXED,
                           __HIP_MEMORY_SCOPE_AGENT);
        vals[0][tid] = 0u;
    }
    __syncthreads();                         // drain finals before arrival
    if (tid == 0) bar_arrive(1u, gcnt, grel, grpcnt);
    // window: bulk set 1 (sources in level 0 -> hdr)
    {
        const unsigned* cr = CNT + (size_t)(256 + b) * NCHUNK;
        unsigned cnt[8]; unsigned tot = 0;
        #pragma unroll
        for (int c = 0; c < 8; ++c) { cnt[c] = cr[c]; tot += cnt[c]; }
        const size_t cb = (size_t)((256 + b) * NCHUNK) * CAP;
        for (unsigned e = tid; e < tot; e += BLOCK) {
            unsigned off = e; int c = 0;
            while (off >= cnt[c]) { off -= cnt[c]; ++c; }
            const unsigned w  = SRT[cb + (size_t)c * CAP + off];
            const unsigned si = w & 0x1FFFFFu;
            if (si < (unsigned)P)
                atomicMax(&vals[1][w >> 21], __float_as_uint(hdr[si] + 1.0f));
        }
    }
    if (tid == 0) bar_wait(1u, grel);
    __syncthreads();

    for (int l = 1; l < NLEVELS; ++l) {
        const int p = l & 1;
        // fresh pass: sources in level l (published at B_l, just observed)
        {
            const unsigned* cr = CNT + (size_t)(l * 256 + b) * NCHUNK;
            unsigned cnt[8]; unsigned tot = 0;
            #pragma unroll
            for (int c = 0; c < 8; ++c) { cnt[c] = cr[c]; tot += cnt[c]; }
            const size_t cb = (size_t)((l * 256 + b) * NCHUNK) * CAP;
            const unsigned lo = (unsigned)(l * P);
            for (unsigned e = tid; e < tot; e += BLOCK) {
                unsigned off = e; int c = 0;
                while (off >= cnt[c]) { off -= cnt[c]; ++c; }
                const unsigned w  = SRT[cb + (size_t)c * CAP + off];
                const unsigned si = w & 0x1FFFFFu;
                if (si >= lo)
                    atomicMax(&vals[p][w >> 21],
                              __float_as_uint(out[si] + 1.0f));
            }
        }
        __syncthreads();
        if (tid < SLICE) {                   // finals level l+1 + rezero
            const int node = (l + 1) * P + b * SLICE + tid;
            unsigned m = vals[p][tid];
            const unsigned hb = __float_as_uint(hdr[node]);
            if (hb > m) m = hb;
            __hip_atomic_store(outu + node, m, __ATOMIC_RELAXED,
                               __HIP_MEMORY_SCOPE_AGENT);
            vals[p][tid] = 0u;
        }
        if (l == NLEVELS - 1) break;         // kernel-end release publishes
        __syncthreads();                     // drain finals before arrival
        if (tid == 0) bar_arrive((unsigned)(l + 1), gcnt, grel, grpcnt);
        // window: bulk set l+1 (sources <= level l, all published)
        {
            const unsigned* cr = CNT + (size_t)((l + 1) * 256 + b) * NCHUNK;
            unsigned cnt[8]; unsigned tot = 0;
            #pragma unroll
            for (int c = 0; c < 8; ++c) { cnt[c] = cr[c]; tot += cnt[c]; }
            const size_t cb = (size_t)(((l + 1) * 256 + b) * NCHUNK) * CAP;
            const unsigned hi = (unsigned)((l + 1) * P);
            for (unsigned e = tid; e < tot; e += BLOCK) {
                unsigned off = e; int c = 0;
                while (off >= cnt[c]) { off -= cnt[c]; ++c; }
                const unsigned w  = SRT[cb + (size_t)c * CAP + off];
                const unsigned si = w & 0x1FFFFFu;
                if (si < hi) {
                    const float x = si < (unsigned)P ? hdr[si] : out[si];
                    atomicMax(&vals[p ^ 1][w >> 21],
                              __float_as_uint(x + 1.0f));
                }
            }
        }
        if (tid == 0) bar_wait((unsigned)(l + 1), grel);
        __syncthreads();
    }
}

extern "C" void kernel_launch(void* const* d_in, const int* in_sizes, int n_in,
                              void* d_out, int out_size, void* d_ws, size_t ws_size,
                              hipStream_t stream) {
    const float* hdr = (const float*)d_in[0];
    const int*   src = (const int*)d_in[1];
    const int*   dst = (const int*)d_in[2];
    float*       out = (float*)d_out;
    unsigned*    ws  = (unsigned*)d_ws;

    ws_init<<<dim3(1), dim3(1024), 0, stream>>>(ws);
    if (ws_size < WS_NEED) {
        // not enough workspace for cells: force the proven fallback path
        (void)hipMemsetAsync((char*)ws + (size_t)FLAG_IDX * 4, 1, 4, stream);
    } else {
        k_scatter<<<dim3(NLEVELS * NCHUNK), dim3(1024), 0, stream>>>(src, dst, ws);
    }

    void* args[] = { (void*)&hdr, (void*)&src, (void*)&dst,
                     (void*)&out, (void*)&ws };
    (void)hipLaunchCooperativeKernel((const void*)pathfinder_main,
                                     dim3(GRID), dim3(BLOCK), args, 0, stream);
}

// Round 12
// 441.209 us; speedup vs baseline: 1.7297x; 1.7297x over previous
//
#include <hip/hip_runtime.h>

// Problem constants (match reference setup_inputs)
constexpr int L = 64;
constexpr int P = 32768;
constexpr int N = L * P;          // 2,097,152 nodes
constexpr int E_PER = 262144;     // edges per non-source level
constexpr int NLEVELS = L - 1;    // 63 edge sets

constexpr int BLOCK = 1024;                 // 16 waves/block, 1 block/CU
constexpr int GRID  = 256;                  // cooperative grid
constexpr int GROUPS = 16;
constexpr int GROUP_SIZE = GRID / GROUPS;
constexpr int SLOT = 32;                    // u32 per barrier slot (128 B)

constexpr int SLICE   = 128;                // nodes per slice = P/256
constexpr int NCHUNK  = 32;                 // chunks per level
constexpr int CHUNK_E = E_PER / NCHUNK;     // 8192 edges per chunk
constexpr int SEG_T   = 32;                 // threads per segment in main

// ws layout (bytes). Compact (unpadded) sorted edges + per-chunk tables.
constexpr int    FLAG_IDX = 768;            // u32 idx: force-fallback flag
constexpr size_t WS_PRE = 4096;             // u32[63][32][257] excl. bucket starts
constexpr size_t WS_NF  = 2097152;          // u32[63][32][256] fresh counts
constexpr size_t WS_SRT = 8388608;          // u32[63][E_PER] sorted packed edges
constexpr size_t WS_NEED = WS_SRT + (size_t)NLEVELS * E_PER * 4;   // ~74.5 MB

typedef float vfloat4 __attribute__((ext_vector_type(4)));

// ---------------- split-phase grid barrier (proven R3-R10) -----------------
__device__ __forceinline__ void bar_arrive(unsigned bar, unsigned* gcnt,
                                           unsigned* grel, unsigned* grpcnt) {
    const unsigned old = __hip_atomic_fetch_add(
        grpcnt, 1u, __ATOMIC_RELAXED, __HIP_MEMORY_SCOPE_AGENT);
    if (old == bar * GROUP_SIZE - 1) {
        const unsigned o2 = __hip_atomic_fetch_add(
            gcnt, 1u, __ATOMIC_RELAXED, __HIP_MEMORY_SCOPE_AGENT);
        if (o2 == bar * GROUPS - 1)
            __hip_atomic_store(grel, bar, __ATOMIC_RELAXED,
                               __HIP_MEMORY_SCOPE_AGENT);
    }
}
__device__ __forceinline__ void bar_wait(unsigned bar, unsigned* grel) {
    while (__hip_atomic_load(grel, __ATOMIC_RELAXED,
                             __HIP_MEMORY_SCOPE_AGENT) < bar)
        __builtin_amdgcn_s_sleep(1);
}

__global__ void __launch_bounds__(1024)
ws_init(unsigned* __restrict__ ws) { ws[threadIdx.x] = 0u; }

// -------- LDS counting-sort scatter: NO scattered global stores ------------
// One block per (level, chunk of 8192). Edges held in registers between the
// rank pass and the placement pass; output written as coalesced int4 runs.
// Segment layout per bucket: [fresh (src in level l) | bulk (src < l*P)].
__global__ void __launch_bounds__(1024)
k_scatter(const int* __restrict__ src, const int* __restrict__ dst,
          unsigned* __restrict__ ws) {
    const int l = blockIdx.x >> 5;
    const int c = blockIdx.x & 31;
    const int tid = threadIdx.x;

    __shared__ unsigned hist[2][256];       // [1]=fresh, [0]=bulk counts
    __shared__ unsigned sp[2][256];         // scan ping-pong
    __shared__ unsigned sbf[256], sbb[256]; // fresh / bulk base per bucket
    __shared__ unsigned sorted[CHUNK_E];    // 32 KB staging

    if (tid < 256) { hist[0][tid] = 0u; hist[1][tid] = 0u; }
    __syncthreads();

    const int e4 = (l * E_PER + c * CHUNK_E) >> 2;    // int4 index base
    unsigned word[2][4], meta[2][4];
    #pragma unroll
    for (int k = 0; k < 2; ++k) {
        const int4 s = ((const int4*)src)[e4 + k * 1024 + tid];
        const int4 d = ((const int4*)dst)[e4 + k * 1024 + tid];
        const int sv[4] = { s.x, s.y, s.z, s.w };
        const int dv[4] = { d.x, d.y, d.z, d.w };
        #pragma unroll
        for (int j = 0; j < 4; ++j) {
            const unsigned si  = (unsigned)sv[j];
            const unsigned loc = (unsigned)(dv[j] - (l + 1) * P);   // 0..P-1
            const unsigned bkt = loc >> 7;
            const unsigned fr  = si >= (unsigned)(l * P) ? 1u : 0u;
            const unsigned rank = atomicAdd(&hist[fr][bkt], 1u);    // LDS
            word[k][j] = si | ((loc & 127u) << 21);
            meta[k][j] = rank | (bkt << 13) | (fr << 21);   // rank<8192
        }
    }
    __syncthreads();

    // 256-entry Hillis-Steele inclusive scan of per-bucket totals
    if (tid < 256) sp[0][tid] = hist[0][tid] + hist[1][tid];
    __syncthreads();
    int pp = 0;
    #pragma unroll
    for (int off = 1; off < 256; off <<= 1) {
        if (tid < 256)
            sp[pp ^ 1][tid] = sp[pp][tid] + (tid >= off ? sp[pp][tid - off] : 0u);
        pp ^= 1;
        __syncthreads();
    }
    if (tid < 256) {
        const unsigned tot  = hist[0][tid] + hist[1][tid];
        const unsigned excl = sp[pp][tid] - tot;
        sbf[tid] = excl;                    // fresh at segment front
        sbb[tid] = excl + hist[1][tid];     // bulk after fresh
    }
    __syncthreads();

    #pragma unroll
    for (int k = 0; k < 2; ++k)
        #pragma unroll
        for (int j = 0; j < 4; ++j) {
            const unsigned m    = meta[k][j];
            const unsigned rank = m & 0x1FFFu;
            const unsigned bkt  = (m >> 13) & 0xFFu;
            const unsigned pos  = ((m >> 21) ? sbf[bkt] : sbb[bkt]) + rank;
            sorted[pos] = word[k][j];       // LDS scatter (cheap)
        }
    __syncthreads();

    // coalesced flush: 32 KB as int4 runs + offset tables
    int4* SRT4 = (int4*)((char*)ws + WS_SRT);
    const int4* s4 = (const int4*)sorted;
    #pragma unroll
    for (int k = 0; k < 2; ++k)
        SRT4[e4 + k * 1024 + tid] = s4[k * 1024 + tid];
    unsigned* PRE = (unsigned*)((char*)ws + WS_PRE);
    unsigned* NF  = (unsigned*)((char*)ws + WS_NF);
    if (tid < 256) {
        PRE[(size_t)(l * NCHUNK + c) * 257 + tid] = sbf[tid];   // == excl
        NF [(size_t)(l * NCHUNK + c) * 256 + tid] = hist[1][tid];
    }
    if (tid == 256) PRE[(size_t)(l * NCHUNK + c) * 257 + 256] = CHUNK_E;
}

// ---------------- main persistent kernel (R9/R10-proven flow) --------------
__global__ void __launch_bounds__(BLOCK, 1)
pathfinder_main(const float* __restrict__ hdr, const int* __restrict__ src,
                const int* __restrict__ dst, float* __restrict__ out,
                unsigned* __restrict__ ws) {
    const int b = blockIdx.x, tid = threadIdx.x, g = b >> 4;
    unsigned* const gcnt   = ws;
    unsigned* const grel   = ws + SLOT;
    unsigned* const grpcnt = ws + (2 + g) * SLOT;
    unsigned* const outu   = (unsigned*)out;

    if (ws[FLAG_IDX] != 0u) {
        // ---- fallback: R7-proven edge-parallel path (global atomics) ----
        const int t = b * BLOCK + tid;
        {
            const vfloat4* hdr4 = (const vfloat4*)hdr;
            const vfloat4 a = hdr4[t];
            const vfloat4 c = hdr4[t + E_PER];
            #pragma unroll
            for (int j = 0; j < 4; ++j) {
                __hip_atomic_store(outu + 4 * t + j, __float_as_uint(a[j]),
                                   __ATOMIC_RELAXED, __HIP_MEMORY_SCOPE_AGENT);
                __hip_atomic_store(outu + 4 * (t + E_PER) + j,
                                   __float_as_uint(c[j]),
                                   __ATOMIC_RELAXED, __HIP_MEMORY_SCOPE_AGENT);
            }
        }
        int si0 = src[t], di0 = dst[t];
        int si1 = src[E_PER + t], di1 = dst[E_PER + t];
        __syncthreads();
        if (tid == 0) { bar_arrive(1u, gcnt, grel, grpcnt); bar_wait(1u, grel); }
        __syncthreads();
        for (int l = 0; l < NLEVELS; ++l) {
            if (si0 >= l * P)
                atomicMax(outu + di0, __float_as_uint(out[si0] + 1.0f));
            if (l == NLEVELS - 1) break;
            __syncthreads();
            if (tid == 0) bar_arrive((unsigned)(l + 2), gcnt, grel, grpcnt);
            int si2 = 0, di2 = 0;
            if (l + 2 < NLEVELS) {
                const size_t base = (size_t)(l + 2) * E_PER;
                si2 = src[base + t]; di2 = dst[base + t];
            }
            if (si1 < (l + 1) * P)
                atomicMax(outu + di1, __float_as_uint(out[si1] + 1.0f));
            if (tid == 0) bar_wait((unsigned)(l + 2), grel);
            __syncthreads();
            si0 = si1; di0 = di1; si1 = si2; di1 = di2;
        }
        return;
    }

    // ---- sorted path: block b owns slice b of every level ----
    const unsigned* PRE = (const unsigned*)((char*)ws + WS_PRE);
    const unsigned* NF  = (const unsigned*)((char*)ws + WS_NF);
    const unsigned* SRT = (const unsigned*)((char*)ws + WS_SRT);
    const int c   = tid >> 5;            // my segment (chunk) 0..31
    const int idx = tid & (SEG_T - 1);   // lane within segment

    __shared__ unsigned vals[2][SLICE];
    if (tid < SLICE) { vals[0][tid] = 0u; vals[1][tid] = 0u; }
    if (tid < SLICE)
        __hip_atomic_store(outu + b * SLICE + tid,
                           __float_as_uint(hdr[b * SLICE + tid]),
                           __ATOMIC_RELAXED, __HIP_MEMORY_SCOPE_AGENT);
    __syncthreads();

    // set 0: all fresh (sources = hdr), processable pre-barrier
    {
        const size_t pb = (size_t)(0 * NCHUNK + c) * 257 + b;
        const unsigned s0 = PRE[pb];
        const unsigned nf = NF[(size_t)(0 * NCHUNK + c) * 256 + b];
        const unsigned sb = (unsigned)(c * CHUNK_E) + s0;
        for (unsigned i = idx; i < nf; i += SEG_T) {
            const unsigned w  = SRT[sb + i];
            const unsigned si = w & 0x1FFFFFu;
            atomicMax(&vals[0][w >> 21], __float_as_uint(hdr[si] + 1.0f));
        }
    }
    __syncthreads();
    if (tid < SLICE) {                       // finals level 1 + rezero
        const int node = P + b * SLICE + tid;
        unsigned m = vals[0][tid];
        const unsigned hb = __float_as_uint(hdr[node]);
        if (hb > m) m = hb;
        __hip_atomic_store(outu + node, m, __ATOMIC_RELAXED,
                           __HIP_MEMORY_SCOPE_AGENT);
        vals[0][tid] = 0u;
    }
    __syncthreads();                         // drain finals before arrival
    if (tid == 0) bar_arrive(1u, gcnt, grel, grpcnt);
    // window: bulk of set 1 (sources level 0 = hdr)
    {
        const size_t pb = (size_t)(1 * NCHUNK + c) * 257 + b;
        const unsigned s0 = PRE[pb], s1 = PRE[pb + 1];
        const unsigned nf = NF[(size_t)(1 * NCHUNK + c) * 256 + b];
        const unsigned sb = (unsigned)(E_PER + c * CHUNK_E) + s0;
        const unsigned len = s1 - s0;
        for (unsigned i = nf + idx; i < len; i += SEG_T) {
            const unsigned w  = SRT[sb + i];
            const unsigned si = w & 0x1FFFFFu;
            atomicMax(&vals[1][w >> 21], __float_as_uint(hdr[si] + 1.0f));
        }
    }
    if (tid == 0) bar_wait(1u, grel);
    __syncthreads();

    for (int l = 1; l < NLEVELS; ++l) {
        const int p = l & 1;
        // fresh pass: segment prefix only (sources in level l, just observed)
        {
            const size_t pb = (size_t)(l * NCHUNK + c) * 257 + b;
            const unsigned s0 = PRE[pb];
            const unsigned nf = NF[(size_t)(l * NCHUNK + c) * 256 + b];
            const unsigned sb = (unsigned)(l * E_PER + c * CHUNK_E) + s0;
            for (unsigned i = idx; i < nf; i += SEG_T) {
                const unsigned w  = SRT[sb + i];
                const unsigned si = w & 0x1FFFFFu;
                atomicMax(&vals[p][w >> 21],
                          __float_as_uint(out[si] + 1.0f));
            }
        }
        __syncthreads();
        if (tid < SLICE) {                   // finals level l+1 + rezero
            const int node = (l + 1) * P + b * SLICE + tid;
            unsigned m = vals[p][tid];
            const unsigned hb = __float_as_uint(hdr[node]);
            if (hb > m) m = hb;
            __hip_atomic_store(outu + node, m, __ATOMIC_RELAXED,
                               __HIP_MEMORY_SCOPE_AGENT);
            vals[p][tid] = 0u;
        }
        if (l == NLEVELS - 1) break;         // kernel-end release publishes
        __syncthreads();                     // drain finals before arrival
        if (tid == 0) bar_arrive((unsigned)(l + 1), gcnt, grel, grpcnt);
        // window: bulk of set l+1 (sources <= level l, all published)
        {
            const size_t pb = (size_t)((l + 1) * NCHUNK + c) * 257 + b;
            const unsigned s0 = PRE[pb], s1 = PRE[pb + 1];
            const unsigned nf = NF[(size_t)((l + 1) * NCHUNK + c) * 256 + b];
            const unsigned sb = (unsigned)((l + 1) * E_PER + c * CHUNK_E) + s0;
            const unsigned len = s1 - s0;
            for (unsigned i = nf + idx; i < len; i += SEG_T) {
                const unsigned w  = SRT[sb + i];
                const unsigned si = w & 0x1FFFFFu;
                const float x = si < (unsigned)P ? hdr[si] : out[si];
                atomicMax(&vals[p ^ 1][w >> 21], __float_as_uint(x + 1.0f));
            }
        }
        if (tid == 0) bar_wait((unsigned)(l + 1), grel);
        __syncthreads();
    }
}

extern "C" void kernel_launch(void* const* d_in, const int* in_sizes, int n_in,
                              void* d_out, int out_size, void* d_ws, size_t ws_size,
                              hipStream_t stream) {
    const float* hdr = (const float*)d_in[0];
    const int*   src = (const int*)d_in[1];
    const int*   dst = (const int*)d_in[2];
    float*       out = (float*)d_out;
    unsigned*    ws  = (unsigned*)d_ws;

    ws_init<<<dim3(1), dim3(1024), 0, stream>>>(ws);
    if (ws_size < WS_NEED) {
        (void)hipMemsetAsync((char*)ws + (size_t)FLAG_IDX * 4, 1, 4, stream);
    } else {
        k_scatter<<<dim3(NLEVELS * NCHUNK), dim3(1024), 0, stream>>>(src, dst, ws);
    }

    void* args[] = { (void*)&hdr, (void*)&src, (void*)&dst,
                     (void*)&out, (void*)&ws };
    (void)hipLaunchCooperativeKernel((const void*)pathfinder_main,
                                     dim3(GRID), dim3(BLOCK), args, 0, stream);
}